// Round 11
// baseline (2386.137 us; speedup 1.0000x reference)
//
#include <hip/hip_runtime.h>
#include <hip/hip_bf16.h>

#define B_   64
#define N_   1024
#define IND_ 128
#define HID_ 32

typedef __attribute__((ext_vector_type(8))) short short8;
typedef __attribute__((ext_vector_type(4))) float f32x4;
typedef unsigned short u16;

static __device__ __forceinline__ u16 f2bf(float f) {
    union { __hip_bfloat16 h; u16 s; } u;
    u.h = __float2bfloat16(f);
    return u.s;
}
static __device__ __forceinline__ short8 cvt8(f32x4 v0, f32x4 v1) {
    union { short8 s; __hip_bfloat162 h[4]; } u;
    u.h[0] = __float22bfloat162_rn(float2{v0[0], v0[1]});
    u.h[1] = __float22bfloat162_rn(float2{v0[2], v0[3]});
    u.h[2] = __float22bfloat162_rn(float2{v1[0], v1[1]});
    u.h[3] = __float22bfloat162_rn(float2{v1[2], v1[3]});
    return u.s;
}

struct UArgs {
    const float* adjf; const float* x;
    const float* W[4]; const float* bi[4]; const float* al[4];
    u16* adjT; u16* hFA; u16* hFB; float* partial; float* out;
    int* ctrl;   // [0]=next pop counter; +16: dlin[64]; +80: dagg[4*64]
};

// ---------------- persistent work-stealing uber-kernel ---------------------
// Items (popped via atomic): [0,64) linear1(batch) | [64,4160) agg(l,b,bx)
// layer-major/batch-minor | [4160,4224) finalize(batch).
// Deps: agg(0,b,*) <- dlin[b]==1; agg(l,b,*) <- dagg[l-1][b]==16;
// finalize(b) <- dagg[3][b]==16. Every spinner waits only on lower-index
// items => deadlock-free under any block scheduling. Agent-scope
// acquire/release (+__threadfence) handles cross-XCD L2 non-coherence.
__global__ __launch_bounds__(512, 8) void uber_kernel(UArgs A)
{
    __shared__ int s_item;
    union USm {
        struct {
            float accx[4][64][8];   // K-half exchange (8 KB)
            float h_s[64][33];
            float sW2[HID_][HID_];
            float pool[4][HID_];
        } g;
        float sW1[IND_][HID_];      // linear1 weights (16 KB)
    };
    __shared__ USm sm;

    const int tid = threadIdx.x;
    int* nextp = A.ctrl;
    int* dlin  = A.ctrl + 16;
    int* dagg  = A.ctrl + 80;

    for (;;) {
        __syncthreads();            // guards sm + s_item reuse across items
        if (tid == 0)
            s_item = __hip_atomic_fetch_add(nextp, 1, __ATOMIC_RELAXED,
                                            __HIP_MEMORY_SCOPE_AGENT);
        __syncthreads();
        const int it = s_item;
        if (it >= 64 + 4096 + 64) break;

        if (it < 64) {
            // ---------------- linear1 for batch it -> hFA (fragment layout)
            const int b = it;
            for (int e = tid; e < IND_ * HID_; e += 512)
                ((float*)sm.sW1)[e] = A.W[0][e];
            __syncthreads();
            for (int half = 0; half < 2; ++half) {
                const int n = half * 512 + tid;
                const f32x4* row4 = (const f32x4*)(A.x + ((size_t)b * N_ + n) * IND_);
                float acc[HID_];
#pragma unroll
                for (int o = 0; o < HID_; ++o) acc[o] = 0.f;
#pragma unroll 4
                for (int f4 = 0; f4 < IND_ / 4; ++f4) {
                    f32x4 xv = __builtin_nontemporal_load(row4 + f4);
#pragma unroll
                    for (int j = 0; j < 4; ++j)
#pragma unroll
                        for (int o = 0; o < HID_; ++o)
                            acc[o] += xv[j] * sm.sW1[f4 * 4 + j][o];
                }
                u16* op = A.hFA + (size_t)b * 32768 + (size_t)(n >> 5) * 1024
                          + ((n >> 3) & 3) * 128 + (n & 7);
#pragma unroll
                for (int o = 0; o < HID_; ++o)
                    op[(o >> 4) * 512 + (o & 15) * 8] = f2bf(acc[o]);
            }
            __syncthreads();
            __threadfence();
            if (tid == 0)
                __hip_atomic_fetch_add(&dlin[b], 1, __ATOMIC_RELEASE,
                                       __HIP_MEMORY_SCOPE_AGENT);
        } else if (it < 64 + 4096) {
            // ---------------- agg item (l, b, bx): 64 rows, full K
            const int q = it - 64;
            const int l = q >> 10;
            const int b = (q >> 4) & 63;
            const int bx = q & 15;

            if (tid == 0) {
                if (l == 0) {
                    while (__hip_atomic_load(&dlin[b], __ATOMIC_ACQUIRE,
                                             __HIP_MEMORY_SCOPE_AGENT) < 1)
                        __builtin_amdgcn_s_sleep(2);
                } else {
                    while (__hip_atomic_load(&dagg[(l - 1) * 64 + b], __ATOMIC_ACQUIRE,
                                             __HIP_MEMORY_SCOPE_AGENT) < 16)
                        __builtin_amdgcn_s_sleep(2);
                }
            }
            __syncthreads();

            const u16* hF_in = (l & 1) ? A.hFB : A.hFA;
            u16* hF_out      = (l & 1) ? A.hFA : A.hFB;
            const float* Wn = (l < 3) ? A.W[l + 1] : nullptr;

            const int wid = tid >> 6, lane = tid & 63;
            const int kh = wid >> 2, wt = wid & 3;
            const int r16 = lane & 15, g = lane >> 4;
            const int rowbase = bx * 64 + wt * 16;

            if (l < 3) {
                for (int e = tid; e < HID_ * HID_; e += 512)
                    ((float*)sm.g.sW2)[e] = Wn[e];
            }

            const u16* pbF = hF_in + (size_t)b * 32768 + (size_t)kh * 16384 + lane * 8;
            f32x4 acc[2] = {};

            if (l == 0) {
                // fused: fp32 adj read (nt) + convert + adjT write + MFMA
                const float* pf = A.adjf + ((size_t)b * N_ + rowbase + r16) * N_
                                  + kh * 512 + g * 8;
                u16* po = A.adjT + ((size_t)b * 2048 + (size_t)(bx * 4 + wt) * 32
                                    + kh * 16) * 512 + lane * 8;
#pragma unroll 4
                for (int ki = 0; ki < 16; ++ki) {
                    f32x4 v0 = __builtin_nontemporal_load((const f32x4*)(pf + ki * 32));
                    f32x4 v1 = __builtin_nontemporal_load((const f32x4*)(pf + ki * 32) + 1);
                    short8 a0 = cvt8(v0, v1);
                    *(short8*)(po + (size_t)ki * 512) = a0;
                    short8 b0 = *(const short8*)(pbF + (size_t)ki * 1024);
                    short8 b1 = *(const short8*)(pbF + (size_t)ki * 1024 + 512);
                    acc[0] = __builtin_amdgcn_mfma_f32_16x16x32_bf16(a0, b0, acc[0], 0, 0, 0);
                    acc[1] = __builtin_amdgcn_mfma_f32_16x16x32_bf16(a0, b1, acc[1], 0, 0, 0);
                }
            } else {
                const u16* pa = A.adjT + ((size_t)b * 2048 + (size_t)(bx * 4 + wt) * 32
                                          + kh * 16) * 512 + lane * 8;
#pragma unroll 8
                for (int ki = 0; ki < 16; ++ki) {
                    short8 a0 = *(const short8*)(pa + (size_t)ki * 512);
                    short8 b0 = *(const short8*)(pbF + (size_t)ki * 1024);
                    short8 b1 = *(const short8*)(pbF + (size_t)ki * 1024 + 512);
                    acc[0] = __builtin_amdgcn_mfma_f32_16x16x32_bf16(a0, b0, acc[0], 0, 0, 0);
                    acc[1] = __builtin_amdgcn_mfma_f32_16x16x32_bf16(a0, b1, acc[1], 0, 0, 0);
                }
            }

            // K-half combine
            if (kh == 1) {
#pragma unroll
                for (int ct = 0; ct < 2; ++ct)
#pragma unroll
                    for (int r = 0; r < 4; ++r)
                        sm.g.accx[wt][lane][ct * 4 + r] = acc[ct][r];
            }
            __syncthreads();

            if (kh == 0) {
                const float alpha = *A.al[l];
                float v[2][4], ps[2];
#pragma unroll
                for (int ct = 0; ct < 2; ++ct) {
                    const float bv = A.bi[l][ct * 16 + r16];
                    ps[ct] = 0.f;
#pragma unroll
                    for (int r = 0; r < 4; ++r) {
                        float xv = acc[ct][r] + sm.g.accx[wt][lane][ct * 4 + r] + bv;
                        xv = (xv >= 0.f) ? xv : alpha * xv;
                        v[ct][r] = xv;
                        ps[ct] += xv;
                    }
                }
#pragma unroll
                for (int ct = 0; ct < 2; ++ct) {
                    const int col = ct * 16 + r16;
                    float p = ps[ct];
                    p += __shfl_xor(p, 16, 64);
                    p += __shfl_xor(p, 32, 64);
                    if (lane < 16) sm.g.pool[wt][col] = p;
                    if (l < 3) {
#pragma unroll
                        for (int r = 0; r < 4; ++r)
                            sm.g.h_s[wt * 16 + g * 4 + r][col] = v[ct][r];
                    }
                }
            }
            __syncthreads();

            if (tid < HID_) {
                float s = sm.g.pool[0][tid] + sm.g.pool[1][tid]
                        + sm.g.pool[2][tid] + sm.g.pool[3][tid];
                A.partial[(((size_t)l * B_ + b) * 16 + bx) * HID_ + tid] = s;
            }

            if (l < 3) {
                // fused next-layer linear -> hF_out (fragment layout)
                const int r_local = tid >> 3;
                const int obase = (tid & 7) * 4;
                float acc2[4];
#pragma unroll
                for (int o = 0; o < 4; ++o) acc2[o] = 0.f;
#pragma unroll 4
                for (int k = 0; k < HID_; ++k) {
                    const float hv = sm.g.h_s[r_local][k];
#pragma unroll
                    for (int o = 0; o < 4; ++o) acc2[o] += hv * sm.g.sW2[k][obase + o];
                }
                const int n = bx * 64 + r_local;
                u16* op = hF_out + (size_t)b * 32768 + (size_t)(n >> 5) * 1024
                          + ((n >> 3) & 3) * 128 + (n & 7);
#pragma unroll
                for (int o = 0; o < 4; ++o) {
                    const int oo = obase + o;
                    op[(oo >> 4) * 512 + (oo & 15) * 8] = f2bf(acc2[o]);
                }
            }
            __syncthreads();
            __threadfence();
            if (tid == 0)
                __hip_atomic_fetch_add(&dagg[l * 64 + b], 1, __ATOMIC_RELEASE,
                                       __HIP_MEMORY_SCOPE_AGENT);
        } else {
            // ---------------- finalize(batch): out[b][l*32+o]
            const int b = it - (64 + 4096);
            if (tid == 0) {
                while (__hip_atomic_load(&dagg[3 * 64 + b], __ATOMIC_ACQUIRE,
                                         __HIP_MEMORY_SCOPE_AGENT) < 16)
                    __builtin_amdgcn_s_sleep(2);
            }
            __syncthreads();
            if (tid < 128) {
                const int l = tid >> 5, o = tid & 31;
                const float* p = A.partial + (((size_t)l * B_ + b) * 16) * HID_ + o;
                float s = 0.f;
#pragma unroll
                for (int t = 0; t < 16; ++t) s += p[t * HID_];
                A.out[b * 128 + l * HID_ + o] = s;
            }
        }
    }
}

// ================= fallback path (ws too small): R10 MODE2 =================
template<int F>
__global__ __launch_bounds__(256) void linear_kernel(
    const float* __restrict__ in, const float* __restrict__ W,
    u16* __restrict__ hF)
{
    __shared__ float sW[F][HID_];
    const int tid = threadIdx.x;
    for (int e = tid; e < F * HID_; e += 256) sW[e / HID_][e % HID_] = W[e];
    __syncthreads();
    const int b = blockIdx.x >> 2;
    const int n = ((blockIdx.x & 3) << 8) + tid;
    const f32x4* row4 = (const f32x4*)(in + ((size_t)b * N_ + n) * F);
    float acc[HID_];
#pragma unroll
    for (int o = 0; o < HID_; ++o) acc[o] = 0.f;
#pragma unroll 4
    for (int f4 = 0; f4 < F / 4; ++f4) {
        f32x4 xv = __builtin_nontemporal_load(row4 + f4);
#pragma unroll
        for (int j = 0; j < 4; ++j)
#pragma unroll
            for (int o = 0; o < HID_; ++o) acc[o] += xv[j] * sW[f4 * 4 + j][o];
    }
    u16* op = hF + (size_t)b * (HID_ * N_) + (size_t)(n >> 5) * 1024
              + ((n >> 3) & 3) * 128 + (n & 7);
#pragma unroll
    for (int o = 0; o < HID_; ++o)
        op[(o >> 4) * 512 + (o & 15) * 8] = f2bf(acc[o]);
}

__global__ __launch_bounds__(512, 8) void agg_mode2_kernel(
    const float* __restrict__ adjf, const u16* __restrict__ hF_in,
    float* __restrict__ h, float* __restrict__ partial,
    const float* __restrict__ bias, const float* __restrict__ alpha_p)
{
    __shared__ float accx[4][64][8];
    __shared__ float pool[4][HID_];
    const int tid = threadIdx.x;
    const int b = blockIdx.y, bx = blockIdx.x;
    const int wid = tid >> 6, lane = tid & 63;
    const int kh = wid >> 2, wt = wid & 3;
    const int r16 = lane & 15, g = lane >> 4;
    const int rowbase = bx * 64 + wt * 16;
    const u16* pbF = hF_in + (size_t)b * 32768 + (size_t)kh * 16384 + lane * 8;
    const float* pf = adjf + ((size_t)b * N_ + rowbase + r16) * N_ + kh * 512 + g * 8;
    f32x4 acc[2] = {};
#pragma unroll 4
    for (int ki = 0; ki < 16; ++ki) {
        f32x4 v0 = __builtin_nontemporal_load((const f32x4*)(pf + ki * 32));
        f32x4 v1 = __builtin_nontemporal_load((const f32x4*)(pf + ki * 32) + 1);
        short8 a0 = cvt8(v0, v1);
        short8 b0 = *(const short8*)(pbF + (size_t)ki * 1024);
        short8 b1 = *(const short8*)(pbF + (size_t)ki * 1024 + 512);
        acc[0] = __builtin_amdgcn_mfma_f32_16x16x32_bf16(a0, b0, acc[0], 0, 0, 0);
        acc[1] = __builtin_amdgcn_mfma_f32_16x16x32_bf16(a0, b1, acc[1], 0, 0, 0);
    }
    if (kh == 1) {
#pragma unroll
        for (int ct = 0; ct < 2; ++ct)
#pragma unroll
            for (int r = 0; r < 4; ++r) accx[wt][lane][ct * 4 + r] = acc[ct][r];
    }
    __syncthreads();
    if (kh == 0) {
        const float alpha = *alpha_p;
        float ps[2];
#pragma unroll
        for (int ct = 0; ct < 2; ++ct) {
            const float bv = bias[ct * 16 + r16];
            ps[ct] = 0.f;
#pragma unroll
            for (int r = 0; r < 4; ++r) {
                float xv = acc[ct][r] + accx[wt][lane][ct * 4 + r] + bv;
                xv = (xv >= 0.f) ? xv : alpha * xv;
                h[((size_t)b * N_ + rowbase + g * 4 + r) * HID_ + ct * 16 + r16] = xv;
                ps[ct] += xv;
            }
        }
#pragma unroll
        for (int ct = 0; ct < 2; ++ct) {
            float p = ps[ct];
            p += __shfl_xor(p, 16, 64);
            p += __shfl_xor(p, 32, 64);
            if (lane < 16) pool[wt][ct * 16 + r16] = p;
        }
    }
    __syncthreads();
    if (tid < HID_) {
        float s = pool[0][tid] + pool[1][tid] + pool[2][tid] + pool[3][tid];
        partial[((size_t)b * 16 + bx) * HID_ + tid] = s;
    }
}

__global__ __launch_bounds__(256) void finalize_kernel(
    const float* __restrict__ partial, float* __restrict__ out)
{
    const int i = blockIdx.x * 256 + threadIdx.x;
    if (i >= B_ * 4 * HID_) return;
    const int b = i >> 7;
    const int rem = i & 127;
    const int l = rem >> 5;
    const int o = rem & 31;
    const float* p = partial + (((size_t)l * B_ + b) * 16) * HID_ + o;
    float s = 0.f;
#pragma unroll
    for (int t = 0; t < 16; ++t) s += p[t * HID_];
    out[i] = s;
}

extern "C" void kernel_launch(void* const* d_in, const int* in_sizes, int n_in,
                              void* d_out, int out_size, void* d_ws, size_t ws_size,
                              hipStream_t stream) {
    const float* x   = (const float*)d_in[0];
    const float* adj = (const float*)d_in[1];
    const float* W[4]  = {(const float*)d_in[2], (const float*)d_in[3],
                          (const float*)d_in[4], (const float*)d_in[5]};
    const float* bi[4] = {(const float*)d_in[6], (const float*)d_in[7],
                          (const float*)d_in[8], (const float*)d_in[9]};
    const float* al[4] = {(const float*)d_in[10], (const float*)d_in[11],
                          (const float*)d_in[12], (const float*)d_in[13]};
    float* out = (float*)d_out;

    const size_t ctrl_bytes = 4096;
    const size_t adjb_bytes = (size_t)B_ * N_ * N_ * 2;
    const size_t hlin_bytes = (size_t)B_ * HID_ * N_ * 2;
    const size_t h_bytes    = (size_t)B_ * N_ * HID_ * 4;
    const size_t part_bytes = (size_t)4 * B_ * 16 * HID_ * 4;
    const bool full = ws_size >= ctrl_bytes + adjb_bytes + 2 * hlin_bytes + part_bytes;

    if (full) {
        char* p = (char*)d_ws;
        int*   ctrl = (int*)p;    p += ctrl_bytes;
        u16*   adjT = (u16*)p;    p += adjb_bytes;
        u16*   hFA  = (u16*)p;    p += hlin_bytes;
        u16*   hFB  = (u16*)p;    p += hlin_bytes;
        float* partial = (float*)p;

        hipMemsetAsync(ctrl, 0, ctrl_bytes, stream);

        UArgs a;
        a.adjf = adj; a.x = x;
        for (int i = 0; i < 4; ++i) { a.W[i] = W[i]; a.bi[i] = bi[i]; a.al[i] = al[i]; }
        a.adjT = adjT; a.hFA = hFA; a.hFB = hFB; a.partial = partial; a.out = out;
        a.ctrl = ctrl;

        uber_kernel<<<1024, 512, 0, stream>>>(a);
    } else {
        char* p = (char*)d_ws;
        u16*   hF      = (u16*)p;  p += hlin_bytes;
        float* h       = (float*)p; p += h_bytes;
        float* partial = (float*)p;
        const dim3 ga(16, 64);
        const int part_stride = B_ * 16 * HID_;

        linear_kernel<IND_><<<256, 256, 0, stream>>>(x, W[0], hF);
        agg_mode2_kernel<<<ga, 512, 0, stream>>>(adj, hF, h, partial, bi[0], al[0]);
        for (int l = 1; l < 4; ++l) {
            linear_kernel<HID_><<<256, 256, 0, stream>>>(h, W[l], hF);
            agg_mode2_kernel<<<ga, 512, 0, stream>>>(adj, hF, h,
                                                     partial + (size_t)l * part_stride,
                                                     bi[l], al[l]);
        }
        finalize_kernel<<<32, 256, 0, stream>>>(partial, out);
    }
}

// Round 12
// 414.643 us; speedup vs baseline: 5.7547x; 5.7547x over previous
//
#include <hip/hip_runtime.h>
#include <hip/hip_bf16.h>

#define B_   64
#define N_   1024
#define IND_ 128
#define HID_ 32

typedef __attribute__((ext_vector_type(8))) short short8;
typedef __attribute__((ext_vector_type(4))) float f32x4;
typedef unsigned short u16;

static __device__ __forceinline__ u16 f2bf(float f) {
    union { __hip_bfloat16 h; u16 s; } u;
    u.h = __float2bfloat16(f);
    return u.s;
}
static __device__ __forceinline__ short8 cvt8(f32x4 v0, f32x4 v1) {
    union { short8 s; __hip_bfloat162 h[4]; } u;
    u.h[0] = __float22bfloat162_rn(float2{v0[0], v0[1]});
    u.h[1] = __float22bfloat162_rn(float2{v0[2], v0[3]});
    u.h[2] = __float22bfloat162_rn(float2{v1[0], v1[1]});
    u.h[3] = __float22bfloat162_rn(float2{v1[2], v1[3]});
    return u.s;
}

// ---- linear: hF[b] in B-FRAGMENT layout:
// u16 idx = b*32768 + ki*1024 + b01*512 + lane*8 + j
//   = bf16( hlin[b][n = ki*32 + (lane>>4)*8 + j][o = b01*16 + (lane&15)] )
// Also zeroes the 64 per-batch finalize flags (replay-safe reset: runs
// before agg4 in stream order every call).
template<int F>
__global__ __launch_bounds__(256) void linear_kernel(
    const float* __restrict__ in,    // [B][N][F] fp32
    const float* __restrict__ W,     // [F][HID]
    u16* __restrict__ hF,            // fragment layout
    int* __restrict__ flags)         // [64] or nullptr
{
    __shared__ float sW[F][HID_];
    const int tid = threadIdx.x;
    if (flags && blockIdx.x == 0 && tid < 64) flags[tid] = 0;
    for (int e = tid; e < F * HID_; e += 256) sW[e / HID_][e % HID_] = W[e];
    __syncthreads();

    const int b = blockIdx.x >> 2;
    const int n = ((blockIdx.x & 3) << 8) + tid;
    const f32x4* row4 = (const f32x4*)(in + ((size_t)b * N_ + n) * F);

    float acc[HID_];
#pragma unroll
    for (int o = 0; o < HID_; ++o) acc[o] = 0.f;

#pragma unroll 4
    for (int f4 = 0; f4 < F / 4; ++f4) {
        f32x4 xv = __builtin_nontemporal_load(row4 + f4);
#pragma unroll
        for (int j = 0; j < 4; ++j)
#pragma unroll
            for (int o = 0; o < HID_; ++o) acc[o] += xv[j] * sW[f4 * 4 + j][o];
    }
    u16* op = hF + (size_t)b * (HID_ * N_) + (size_t)(n >> 5) * 1024
              + ((n >> 3) & 3) * 128 + (n & 7);
#pragma unroll
    for (int o = 0; o < HID_; ++o)
        op[(o >> 4) * 512 + (o & 15) * 8] = f2bf(acc[o]);
}

// ---------------- aggregation, 8-wave K-split blocks -----------------------
// Block (bx, by): 512 thr = 8 waves; wave (wt = wid&3, kh = wid>>2) computes
// rows [bx*64+wt*16, +16) over K-half kh. kh=1 acc joins kh=0 via LDS.
// -> 8192 waves chip-wide (8/SIMD), no LDS in the K-loop, ~21KB LDS.
// MODE 0: A from fragment-tiled bf16 adjT.
// MODE 1: A from fp32 adj (converted in-register), adjT written (layer 1).
// MODE 2: A from fp32 adj only; h written fp32 (fallback).
// FIN: last-arriving block per batch (of 16) reduces partial[0..3] -> out.
template<int MODE, int FUSE, int FIN>
__global__ __launch_bounds__(512, 8) void agg_kernel(
    const float* __restrict__ adjf,     // [B][N][N] fp32      (MODE 1,2)
    u16*        __restrict__ adjT,      // [B][2048][512] bf16 (MODE 0 in, 1 out)
    const u16*  __restrict__ hF_in,     // fragment layout
    u16*        __restrict__ hF_out,    // fragment layout (FUSE)
    const float* __restrict__ Wnext,    // [HID][HID]          (FUSE)
    float*      __restrict__ h,         // [B][N][HID] fp32    (MODE 2)
    float*      __restrict__ partial,   // [B][16][HID] (this layer's slice)
    const float* __restrict__ partial_base, // [4][B][16][HID] (FIN)
    float*      __restrict__ out,       // [B][128]            (FIN)
    int*        __restrict__ flags,     // [64]                (FIN)
    const float* __restrict__ bias,     // [HID]
    const float* __restrict__ alpha_p)  // [1]
{
    __shared__ float accx[4][64][8];    // K-half exchange, 8 KB
    __shared__ float h_s[64][33];
    __shared__ float sW2[HID_][HID_];
    __shared__ float pool[4][HID_];
    __shared__ int s_last;

    const int tid = threadIdx.x;
    const int b = blockIdx.y, bx = blockIdx.x;
    const int wid = tid >> 6, lane = tid & 63;
    const int kh = wid >> 2, wt = wid & 3;
    const int r16 = lane & 15, g = lane >> 4;
    const int rowbase = bx * 64 + wt * 16;

    if (FUSE) {
        for (int e = tid; e < HID_ * HID_; e += 512) ((float*)sW2)[e] = Wnext[e];
    }

    const u16* pbF = hF_in + (size_t)b * (HID_ * N_) + (size_t)kh * 16 * 1024 + lane * 8;

    f32x4 acc[2] = {};
    if (MODE == 0) {
        const u16* pa = adjT +
            ((size_t)b * 2048 + (size_t)(bx * 4 + wt) * 32 + kh * 16) * 512 + lane * 8;
#pragma unroll 8
        for (int ki = 0; ki < 16; ++ki) {
            short8 a0 = *(const short8*)(pa + (size_t)ki * 512);
            short8 b0 = *(const short8*)(pbF + (size_t)ki * 1024);
            short8 b1 = *(const short8*)(pbF + (size_t)ki * 1024 + 512);
            acc[0] = __builtin_amdgcn_mfma_f32_16x16x32_bf16(a0, b0, acc[0], 0, 0, 0);
            acc[1] = __builtin_amdgcn_mfma_f32_16x16x32_bf16(a0, b1, acc[1], 0, 0, 0);
        }
    } else {
        const float* pf = adjf + ((size_t)b * N_ + rowbase + r16) * N_ + kh * 512 + g * 8;
        u16* po = (MODE == 1)
            ? adjT + ((size_t)b * 2048 + (size_t)(bx * 4 + wt) * 32 + kh * 16) * 512 + lane * 8
            : nullptr;
#pragma unroll 8
        for (int ki = 0; ki < 16; ++ki) {
            // nt: dead fp32 stream must not evict the bf16 working set
            f32x4 v0 = __builtin_nontemporal_load((const f32x4*)(pf + ki * 32));
            f32x4 v1 = __builtin_nontemporal_load((const f32x4*)(pf + ki * 32) + 1);
            short8 a0 = cvt8(v0, v1);
            if (MODE == 1) *(short8*)(po + (size_t)ki * 512) = a0;
            short8 b0 = *(const short8*)(pbF + (size_t)ki * 1024);
            short8 b1 = *(const short8*)(pbF + (size_t)ki * 1024 + 512);
            acc[0] = __builtin_amdgcn_mfma_f32_16x16x32_bf16(a0, b0, acc[0], 0, 0, 0);
            acc[1] = __builtin_amdgcn_mfma_f32_16x16x32_bf16(a0, b1, acc[1], 0, 0, 0);
        }
    }

    // combine K-halves
    if (kh == 1) {
#pragma unroll
        for (int ct = 0; ct < 2; ++ct)
#pragma unroll
            for (int r = 0; r < 4; ++r) accx[wt][lane][ct * 4 + r] = acc[ct][r];
    }
    __syncthreads();

    if (kh == 0) {
        const float alpha = *alpha_p;
        float v[2][4], ps[2];
#pragma unroll
        for (int ct = 0; ct < 2; ++ct) {
            const float bv = bias[ct * 16 + r16];
            ps[ct] = 0.f;
#pragma unroll
            for (int r = 0; r < 4; ++r) {
                float x = acc[ct][r] + accx[wt][lane][ct * 4 + r] + bv;
                x = (x >= 0.f) ? x : alpha * x;
                v[ct][r] = x;
                ps[ct] += x;
            }
        }
#pragma unroll
        for (int ct = 0; ct < 2; ++ct) {
            const int col = ct * 16 + r16;
            float p = ps[ct];
            p += __shfl_xor(p, 16, 64);
            p += __shfl_xor(p, 32, 64);
            if (lane < 16) pool[wt][col] = p;
            if (FUSE) {
#pragma unroll
                for (int r = 0; r < 4; ++r)
                    h_s[wt * 16 + g * 4 + r][col] = v[ct][r];
            }
            if (MODE == 2) {
#pragma unroll
                for (int r = 0; r < 4; ++r)
                    h[((size_t)b * N_ + rowbase + g * 4 + r) * HID_ + ct * 16 + r16] = v[ct][r];
            }
        }
    }
    __syncthreads();

    if (tid < HID_) {
        float s = pool[0][tid] + pool[1][tid] + pool[2][tid] + pool[3][tid];
        partial[((size_t)b * 16 + bx) * HID_ + tid] = s;
    }

    if (FUSE) {
        // next-layer linear from h_s (all 512 threads), fragment-layout out
        const int r_local = tid >> 3;          // node 0..63
        const int obase = (tid & 7) * 4;       // 0,4,...,28
        float acc2[4];
#pragma unroll
        for (int o = 0; o < 4; ++o) acc2[o] = 0.f;
#pragma unroll 4
        for (int k = 0; k < HID_; ++k) {
            const float hv = h_s[r_local][k];
#pragma unroll
            for (int o = 0; o < 4; ++o) acc2[o] += hv * sW2[k][obase + o];
        }
        const int n = bx * 64 + r_local;
        u16* op = hF_out + (size_t)b * (HID_ * N_) + (size_t)(n >> 5) * 1024
                  + ((n >> 3) & 3) * 128 + (n & 7);
#pragma unroll
        for (int o = 0; o < 4; ++o) {
            const int oo = obase + o;
            op[(oo >> 4) * 512 + (oo & 15) * 8] = f2bf(acc2[o]);
        }
    }

    if (FIN) {
        // last block of this batch (of 16) reduces partial[0..3][b] -> out[b]
        __syncthreads();                 // own partial slice written
        __threadfence();                 // visible device-wide before flag
        if (tid == 0)
            s_last = __hip_atomic_fetch_add(&flags[b], 1, __ATOMIC_ACQ_REL,
                                            __HIP_MEMORY_SCOPE_AGENT);
        __syncthreads();
        if (s_last == 15 && tid < 128) { // deterministic: fixed t-order sum
            const int l = tid >> 5, o = tid & 31;
            const float* p = partial_base + (((size_t)l * B_ + b) * 16) * HID_ + o;
            float s = 0.f;
#pragma unroll
            for (int t = 0; t < 16; ++t) s += p[t * HID_];
            out[b * 128 + l * HID_ + o] = s;
        }
    }
}

// ---------------- finalize (fallback path only) ----------------------------
__global__ __launch_bounds__(256) void finalize_kernel(
    const float* __restrict__ partial,  // [4][B][16][HID]
    float* __restrict__ out)            // [B][4*HID]
{
    const int i = blockIdx.x * 256 + threadIdx.x;
    if (i >= B_ * 4 * HID_) return;
    const int b = i >> 7;
    const int rem = i & 127;
    const int l = rem >> 5;
    const int o = rem & 31;
    const float* p = partial + (((size_t)l * B_ + b) * 16) * HID_ + o;
    float s = 0.f;
#pragma unroll
    for (int t = 0; t < 16; ++t) s += p[t * HID_];
    out[i] = s;
}

extern "C" void kernel_launch(void* const* d_in, const int* in_sizes, int n_in,
                              void* d_out, int out_size, void* d_ws, size_t ws_size,
                              hipStream_t stream) {
    const float* x   = (const float*)d_in[0];
    const float* adj = (const float*)d_in[1];
    const float* W[4]  = {(const float*)d_in[2], (const float*)d_in[3],
                          (const float*)d_in[4], (const float*)d_in[5]};
    const float* bi[4] = {(const float*)d_in[6], (const float*)d_in[7],
                          (const float*)d_in[8], (const float*)d_in[9]};
    const float* al[4] = {(const float*)d_in[10], (const float*)d_in[11],
                          (const float*)d_in[12], (const float*)d_in[13]};
    float* out = (float*)d_out;

    const size_t flag_bytes = 256;                      // 64 ints
    const size_t adjb_bytes = (size_t)B_ * N_ * N_ * 2;
    const size_t hlin_bytes = (size_t)B_ * HID_ * N_ * 2;
    const size_t h_bytes    = (size_t)B_ * N_ * HID_ * 4;
    const size_t part_bytes = (size_t)4 * B_ * 16 * HID_ * 4;
    const bool full = ws_size >= flag_bytes + adjb_bytes + 2 * hlin_bytes + part_bytes;

    const dim3 ga(16, 64);
    const int part_stride = B_ * 16 * HID_;

    if (full) {
        char* p = (char*)d_ws;
        int*   flags = (int*)p;   p += flag_bytes;
        u16*   adjT  = (u16*)p;   p += adjb_bytes;
        u16*   hFA   = (u16*)p;   p += hlin_bytes;
        u16*   hFB   = (u16*)p;   p += hlin_bytes;
        float* partial = (float*)p;

        linear_kernel<IND_><<<256, 256, 0, stream>>>(x, W[0], hFA, flags);
        // layer 1: fused fp32 read + in-register convert + adjT write
        agg_kernel<1, 1, 0><<<ga, 512, 0, stream>>>(adj, adjT, hFA, hFB,
                                                    W[1], nullptr,
                                                    partial + 0, nullptr, nullptr, nullptr,
                                                    bi[0], al[0]);
        agg_kernel<0, 1, 0><<<ga, 512, 0, stream>>>(nullptr, adjT, hFB, hFA,
                                                    W[2], nullptr,
                                                    partial + (size_t)1 * part_stride,
                                                    nullptr, nullptr, nullptr,
                                                    bi[1], al[1]);
        agg_kernel<0, 1, 0><<<ga, 512, 0, stream>>>(nullptr, adjT, hFA, hFB,
                                                    W[3], nullptr,
                                                    partial + (size_t)2 * part_stride,
                                                    nullptr, nullptr, nullptr,
                                                    bi[2], al[2]);
        // layer 4: no fuse; last block per batch reduces all layers -> out
        agg_kernel<0, 0, 1><<<ga, 512, 0, stream>>>(nullptr, adjT, hFB, nullptr,
                                                    nullptr, nullptr,
                                                    partial + (size_t)3 * part_stride,
                                                    partial, out, flags,
                                                    bi[3], al[3]);
    } else {
        // fallback: no adjT copy; A from fp32 adj each layer, h fp32 roundtrip
        char* p = (char*)d_ws;
        u16*   hF      = (u16*)p;  p += hlin_bytes;
        float* h       = (float*)p; p += h_bytes;
        float* partial = (float*)p;

        linear_kernel<IND_><<<256, 256, 0, stream>>>(x, W[0], hF, nullptr);
        agg_kernel<2, 0, 0><<<ga, 512, 0, stream>>>(adj, nullptr, hF, nullptr,
                                                    nullptr, h, partial,
                                                    nullptr, nullptr, nullptr,
                                                    bi[0], al[0]);
        for (int l = 1; l < 4; ++l) {
            linear_kernel<HID_><<<256, 256, 0, stream>>>(h, W[l], hF, nullptr);
            agg_kernel<2, 0, 0><<<ga, 512, 0, stream>>>(adj, nullptr, hF, nullptr,
                                                        nullptr, h,
                                                        partial + (size_t)l * part_stride,
                                                        nullptr, nullptr, nullptr,
                                                        bi[l], al[l]);
        }
        finalize_kernel<<<32, 256, 0, stream>>>(partial, out);
    }
}

// Round 13
// 199.838 us; speedup vs baseline: 11.9404x; 2.0749x over previous
//
#include <hip/hip_runtime.h>
#include <hip/hip_bf16.h>

// R13 = exact revert to R10 (199.4 us, best measured).
// Lessons locked in from R8/R11/R12: on MI355X, grid.sync, per-block
// device-scope atomic spin-wait, and per-block __threadfence all cost
// 100s of us (8 non-coherent XCD L2s). Multi-kernel launch boundaries
// (~2 us each) are the cheap mechanism for global ordering.

#define B_   64
#define N_   1024
#define IND_ 128
#define HID_ 32

typedef __attribute__((ext_vector_type(8))) short short8;
typedef __attribute__((ext_vector_type(4))) float f32x4;
typedef unsigned short u16;

static __device__ __forceinline__ u16 f2bf(float f) {
    union { __hip_bfloat16 h; u16 s; } u;
    u.h = __float2bfloat16(f);
    return u.s;
}
static __device__ __forceinline__ short8 cvt8(f32x4 v0, f32x4 v1) {
    union { short8 s; __hip_bfloat162 h[4]; } u;
    u.h[0] = __float22bfloat162_rn(float2{v0[0], v0[1]});
    u.h[1] = __float22bfloat162_rn(float2{v0[2], v0[3]});
    u.h[2] = __float22bfloat162_rn(float2{v1[0], v1[1]});
    u.h[3] = __float22bfloat162_rn(float2{v1[2], v1[3]});
    return u.s;
}

// ---- linear: hF[b] in B-FRAGMENT layout:
// u16 idx = b*32768 + ki*1024 + b01*512 + lane*8 + j
//   = bf16( hlin[b][n = ki*32 + (lane>>4)*8 + j][o = b01*16 + (lane&15)] )
template<int F>
__global__ __launch_bounds__(256) void linear_kernel(
    const float* __restrict__ in,    // [B][N][F] fp32
    const float* __restrict__ W,     // [F][HID]
    u16* __restrict__ hF)            // fragment layout
{
    __shared__ float sW[F][HID_];
    const int tid = threadIdx.x;
    for (int e = tid; e < F * HID_; e += 256) sW[e / HID_][e % HID_] = W[e];
    __syncthreads();

    const int b = blockIdx.x >> 2;
    const int n = ((blockIdx.x & 3) << 8) + tid;
    const f32x4* row4 = (const f32x4*)(in + ((size_t)b * N_ + n) * F);

    float acc[HID_];
#pragma unroll
    for (int o = 0; o < HID_; ++o) acc[o] = 0.f;

#pragma unroll 4
    for (int f4 = 0; f4 < F / 4; ++f4) {
        f32x4 xv = __builtin_nontemporal_load(row4 + f4);
#pragma unroll
        for (int j = 0; j < 4; ++j)
#pragma unroll
            for (int o = 0; o < HID_; ++o) acc[o] += xv[j] * sW[f4 * 4 + j][o];
    }
    u16* op = hF + (size_t)b * (HID_ * N_) + (size_t)(n >> 5) * 1024
              + ((n >> 3) & 3) * 128 + (n & 7);
#pragma unroll
    for (int o = 0; o < HID_; ++o)
        op[(o >> 4) * 512 + (o & 15) * 8] = f2bf(acc[o]);
}

// ---------------- aggregation, 8-wave K-split blocks -----------------------
// Block (bx, by): 512 thr = 8 waves; wave (wt = wid&3, kh = wid>>2) computes
// rows [bx*64+wt*16, +16) over K-half kh. kh=1 acc joins kh=0 via LDS.
// -> 8192 waves chip-wide (8/SIMD), no LDS in the K-loop, ~21KB LDS,
//    1024 blocks = 4/CU all co-resident (no tail).
// MODE 0: A from fragment-tiled bf16 adjT.
// MODE 1: A from fp32 adj (converted in-register), adjT written (layer 1).
// MODE 2: A from fp32 adj only; h written fp32 (fallback).
template<int MODE, int FUSE>
__global__ __launch_bounds__(512, 8) void agg_kernel(
    const float* __restrict__ adjf,     // [B][N][N] fp32      (MODE 1,2)
    u16*        __restrict__ adjT,      // [B][2048][512] bf16 (MODE 0 in, 1 out)
    const u16*  __restrict__ hF_in,     // fragment layout
    u16*        __restrict__ hF_out,    // fragment layout (FUSE)
    const float* __restrict__ Wnext,    // [HID][HID]          (FUSE)
    float*      __restrict__ h,         // [B][N][HID] fp32    (MODE 2)
    float*      __restrict__ partial,   // [B][16][HID] (this layer's slice)
    const float* __restrict__ bias,     // [HID]
    const float* __restrict__ alpha_p)  // [1]
{
    __shared__ float accx[4][64][8];    // K-half exchange, 8 KB
    __shared__ float h_s[64][33];
    __shared__ float sW2[HID_][HID_];
    __shared__ float pool[4][HID_];

    const int tid = threadIdx.x;
    const int b = blockIdx.y, bx = blockIdx.x;
    const int wid = tid >> 6, lane = tid & 63;
    const int kh = wid >> 2, wt = wid & 3;
    const int r16 = lane & 15, g = lane >> 4;
    const int rowbase = bx * 64 + wt * 16;

    if (FUSE) {
        for (int e = tid; e < HID_ * HID_; e += 512) ((float*)sW2)[e] = Wnext[e];
    }

    const u16* pbF = hF_in + (size_t)b * (HID_ * N_) + (size_t)kh * 16 * 1024 + lane * 8;

    f32x4 acc[2] = {};
    if (MODE == 0) {
        const u16* pa = adjT +
            ((size_t)b * 2048 + (size_t)(bx * 4 + wt) * 32 + kh * 16) * 512 + lane * 8;
#pragma unroll 8
        for (int ki = 0; ki < 16; ++ki) {
            short8 a0 = *(const short8*)(pa + (size_t)ki * 512);
            short8 b0 = *(const short8*)(pbF + (size_t)ki * 1024);
            short8 b1 = *(const short8*)(pbF + (size_t)ki * 1024 + 512);
            acc[0] = __builtin_amdgcn_mfma_f32_16x16x32_bf16(a0, b0, acc[0], 0, 0, 0);
            acc[1] = __builtin_amdgcn_mfma_f32_16x16x32_bf16(a0, b1, acc[1], 0, 0, 0);
        }
    } else {
        const float* pf = adjf + ((size_t)b * N_ + rowbase + r16) * N_ + kh * 512 + g * 8;
        u16* po = (MODE == 1)
            ? adjT + ((size_t)b * 2048 + (size_t)(bx * 4 + wt) * 32 + kh * 16) * 512 + lane * 8
            : nullptr;
#pragma unroll 4
        for (int ki = 0; ki < 16; ++ki) {
            // nt: dead fp32 stream must not evict the bf16 working set
            f32x4 v0 = __builtin_nontemporal_load((const f32x4*)(pf + ki * 32));
            f32x4 v1 = __builtin_nontemporal_load((const f32x4*)(pf + ki * 32) + 1);
            short8 a0 = cvt8(v0, v1);
            if (MODE == 1) *(short8*)(po + (size_t)ki * 512) = a0;
            short8 b0 = *(const short8*)(pbF + (size_t)ki * 1024);
            short8 b1 = *(const short8*)(pbF + (size_t)ki * 1024 + 512);
            acc[0] = __builtin_amdgcn_mfma_f32_16x16x32_bf16(a0, b0, acc[0], 0, 0, 0);
            acc[1] = __builtin_amdgcn_mfma_f32_16x16x32_bf16(a0, b1, acc[1], 0, 0, 0);
        }
    }

    // combine K-halves
    if (kh == 1) {
#pragma unroll
        for (int ct = 0; ct < 2; ++ct)
#pragma unroll
            for (int r = 0; r < 4; ++r) accx[wt][lane][ct * 4 + r] = acc[ct][r];
    }
    __syncthreads();

    if (kh == 0) {
        const float alpha = *alpha_p;
        float v[2][4], ps[2];
#pragma unroll
        for (int ct = 0; ct < 2; ++ct) {
            const float bv = bias[ct * 16 + r16];
            ps[ct] = 0.f;
#pragma unroll
            for (int r = 0; r < 4; ++r) {
                float x = acc[ct][r] + accx[wt][lane][ct * 4 + r] + bv;
                x = (x >= 0.f) ? x : alpha * x;
                v[ct][r] = x;
                ps[ct] += x;
            }
        }
#pragma unroll
        for (int ct = 0; ct < 2; ++ct) {
            const int col = ct * 16 + r16;
            float p = ps[ct];
            p += __shfl_xor(p, 16, 64);
            p += __shfl_xor(p, 32, 64);
            if (lane < 16) pool[wt][col] = p;
            if (FUSE) {
#pragma unroll
                for (int r = 0; r < 4; ++r)
                    h_s[wt * 16 + g * 4 + r][col] = v[ct][r];
            }
            if (MODE == 2) {
#pragma unroll
                for (int r = 0; r < 4; ++r)
                    h[((size_t)b * N_ + rowbase + g * 4 + r) * HID_ + col] = v[ct][r];
            }
        }
    }
    __syncthreads();

    if (tid < HID_) {
        float s = pool[0][tid] + pool[1][tid] + pool[2][tid] + pool[3][tid];
        partial[((size_t)b * 16 + bx) * HID_ + tid] = s;
    }

    if (FUSE) {
        // next-layer linear from h_s (all 512 threads), fragment-layout out
        const int r_local = tid >> 3;          // node 0..63
        const int obase = (tid & 7) * 4;       // 0,4,...,28
        float acc2[4];
#pragma unroll
        for (int o = 0; o < 4; ++o) acc2[o] = 0.f;
#pragma unroll 4
        for (int k = 0; k < HID_; ++k) {
            const float hv = h_s[r_local][k];
#pragma unroll
            for (int o = 0; o < 4; ++o) acc2[o] += hv * sW2[k][obase + o];
        }
        const int n = bx * 64 + r_local;
        u16* op = hF_out + (size_t)b * (HID_ * N_) + (size_t)(n >> 5) * 1024
                  + ((n >> 3) & 3) * 128 + (n & 7);
#pragma unroll
        for (int o = 0; o < 4; ++o) {
            const int oo = obase + o;
            op[(oo >> 4) * 512 + (oo & 15) * 8] = f2bf(acc2[o]);
        }
    }
}

// ---------------- finalize: out[b][l*32+o] = sum_t partial[l][b][t][o] ------
__global__ __launch_bounds__(256) void finalize_kernel(
    const float* __restrict__ partial,  // [4][B][16][HID]
    float* __restrict__ out)            // [B][4*HID]
{
    const int i = blockIdx.x * 256 + threadIdx.x;
    if (i >= B_ * 4 * HID_) return;
    const int b = i >> 7;
    const int rem = i & 127;
    const int l = rem >> 5;
    const int o = rem & 31;
    const float* p = partial + (((size_t)l * B_ + b) * 16) * HID_ + o;
    float s = 0.f;
#pragma unroll
    for (int t = 0; t < 16; ++t) s += p[t * HID_];
    out[i] = s;
}

extern "C" void kernel_launch(void* const* d_in, const int* in_sizes, int n_in,
                              void* d_out, int out_size, void* d_ws, size_t ws_size,
                              hipStream_t stream) {
    const float* x   = (const float*)d_in[0];
    const float* adj = (const float*)d_in[1];
    const float* W[4]  = {(const float*)d_in[2], (const float*)d_in[3],
                          (const float*)d_in[4], (const float*)d_in[5]};
    const float* bi[4] = {(const float*)d_in[6], (const float*)d_in[7],
                          (const float*)d_in[8], (const float*)d_in[9]};
    const float* al[4] = {(const float*)d_in[10], (const float*)d_in[11],
                          (const float*)d_in[12], (const float*)d_in[13]};
    float* out = (float*)d_out;

    const size_t adjb_bytes = (size_t)B_ * N_ * N_ * 2;
    const size_t hlin_bytes = (size_t)B_ * HID_ * N_ * 2;
    const size_t h_bytes    = (size_t)B_ * N_ * HID_ * 4;
    const size_t part_bytes = (size_t)4 * B_ * 16 * HID_ * 4;
    const bool full = ws_size >= adjb_bytes + 2 * hlin_bytes + part_bytes;

    const dim3 ga(16, 64);
    const int part_stride = B_ * 16 * HID_;

    if (full) {
        char* p = (char*)d_ws;
        u16* adjT  = (u16*)p;  p += adjb_bytes;
        u16* hFA   = (u16*)p;  p += hlin_bytes;
        u16* hFB   = (u16*)p;  p += hlin_bytes;
        float* partial = (float*)p;

        linear_kernel<IND_><<<256, 256, 0, stream>>>(x, W[0], hFA);
        // layer 1: fused fp32 read + in-register convert + adjT write
        agg_kernel<1, 1><<<ga, 512, 0, stream>>>(adj, adjT, hFA, hFB,
                                                 W[1], nullptr,
                                                 partial + 0, bi[0], al[0]);
        agg_kernel<0, 1><<<ga, 512, 0, stream>>>(nullptr, adjT, hFB, hFA,
                                                 W[2], nullptr,
                                                 partial + (size_t)1 * part_stride,
                                                 bi[1], al[1]);
        agg_kernel<0, 1><<<ga, 512, 0, stream>>>(nullptr, adjT, hFA, hFB,
                                                 W[3], nullptr,
                                                 partial + (size_t)2 * part_stride,
                                                 bi[2], al[2]);
        agg_kernel<0, 0><<<ga, 512, 0, stream>>>(nullptr, adjT, hFB, nullptr,
                                                 nullptr, nullptr,
                                                 partial + (size_t)3 * part_stride,
                                                 bi[3], al[3]);
        finalize_kernel<<<32, 256, 0, stream>>>(partial, out);
    } else {
        // fallback: no adjT copy; A from fp32 adj each layer, h fp32 roundtrip
        char* p = (char*)d_ws;
        u16*   hF      = (u16*)p;  p += hlin_bytes;
        float* h       = (float*)p; p += h_bytes;
        float* partial = (float*)p;

        linear_kernel<IND_><<<256, 256, 0, stream>>>(x, W[0], hF);
        agg_kernel<2, 0><<<ga, 512, 0, stream>>>(adj, nullptr, hF, nullptr,
                                                 nullptr, h, partial, bi[0], al[0]);
        for (int l = 1; l < 4; ++l) {
            linear_kernel<HID_><<<256, 256, 0, stream>>>(h, W[l], hF);
            agg_kernel<2, 0><<<ga, 512, 0, stream>>>(adj, nullptr, hF, nullptr,
                                                     nullptr, h,
                                                     partial + (size_t)l * part_stride,
                                                     bi[l], al[l]);
        }
        finalize_kernel<<<32, 256, 0, stream>>>(partial, out);
    }
}